// Round 2
// baseline (369.203 us; speedup 1.0000x reference)
//
#include <hip/hip_runtime.h>
#include <hip/hip_bf16.h>

// Problem constants (B=2, T=2048, C=1024, NH=16, NKV=8, HD=64, Q_PER_KV=2)
#define BB 2
#define TT 2048
#define CC 1024
#define NH 16
#define NKV 8
#define HD 64

typedef __attribute__((ext_vector_type(8))) short short8;   // 8 bf16 = 4 VGPRs (MFMA A/B frag)
typedef __attribute__((ext_vector_type(4))) float float4v;  // MFMA C/D frag

__device__ __forceinline__ ushort f2bf(float f) {
    __hip_bfloat16 h = __float2bfloat16(f);
    union { __hip_bfloat16 h; ushort u; } v; v.h = h; return v.u;
}

// ---------------------------------------------------------------------------
// f32 -> bf16 convert (n multiple of 4)
// ---------------------------------------------------------------------------
__global__ __launch_bounds__(256) void conv_kernel(
    const float* __restrict__ src, ushort* __restrict__ dst, int n)
{
    int i = (blockIdx.x * 256 + threadIdx.x) * 4;
    if (i + 3 < n) {
        float4 v = *(const float4*)&src[i];
        dst[i + 0] = f2bf(v.x);
        dst[i + 1] = f2bf(v.y);
        dst[i + 2] = f2bf(v.z);
        dst[i + 3] = f2bf(v.w);
    }
}

// Pack Wq(1024x1024)|Wk(1024x512)|Wv(1024x512) -> bf16 [1024][2048]
__global__ __launch_bounds__(256) void pack_qkv_w_kernel(
    const float* __restrict__ Wq, const float* __restrict__ Wk,
    const float* __restrict__ Wv, ushort* __restrict__ dst)
{
    int idx = blockIdx.x * 256 + threadIdx.x;   // over 1024*2048
    int k = idx >> 11, n = idx & 2047;
    float v;
    if (n < 1024)      v = Wq[k * 1024 + n];
    else if (n < 1536) v = Wk[k * 512 + (n - 1024)];
    else               v = Wv[k * 512 + (n - 1536)];
    dst[idx] = f2bf(v);
}

// ---------------------------------------------------------------------------
// bf16 GEMM: C(MxN) = A(MxK) @ B(KxN); A,B row-major bf16; C f32.
// Tile 128x128, BK=32, 4 waves (each 64x64).
// ---------------------------------------------------------------------------
__global__ __launch_bounds__(256) void gemm_kernel(
    const ushort* __restrict__ A, const ushort* __restrict__ Bm,
    float* __restrict__ Cp, int M, int N, int K, int ldc)
{
    __shared__ ushort As[128][40];   // [m][k], +8 pad
    __shared__ ushort Bs[128][40];   // [n][k] (transposed), +8 pad

    const int m0 = blockIdx.x * 128;
    const int n0 = blockIdx.y * 128;
    const int tid = threadIdx.x;
    const int lane = tid & 63;
    const int w = tid >> 6;
    const int wm = (w >> 1) * 64, wn = (w & 1) * 64;

    float4v acc[4][4] = {};

    for (int k0 = 0; k0 < K; k0 += 32) {
        #pragma unroll
        for (int i = 0; i < 2; i++) {
            int idx = tid + i * 256;
            int r = idx >> 2, q = idx & 3;
            uint4 v = *(const uint4*)&A[(size_t)(m0 + r) * K + k0 + q * 8];
            *(uint4*)&As[r][q * 8] = v;
        }
        #pragma unroll
        for (int i = 0; i < 2; i++) {
            int idx = tid + i * 256;
            int kr = idx >> 4, nc = (idx & 15) * 8;
            ushort tmp[8];
            *(uint4*)tmp = *(const uint4*)&Bm[(size_t)(k0 + kr) * N + n0 + nc];
            #pragma unroll
            for (int j = 0; j < 8; j++) Bs[nc + j][kr] = tmp[j];
        }
        __syncthreads();

        short8 af[4], bf[4];
        #pragma unroll
        for (int t = 0; t < 4; t++) {
            af[t] = *(const short8*)&As[wm + t * 16 + (lane & 15)][(lane >> 4) * 8];
            bf[t] = *(const short8*)&Bs[wn + t * 16 + (lane & 15)][(lane >> 4) * 8];
        }
        #pragma unroll
        for (int rt = 0; rt < 4; rt++)
            #pragma unroll
            for (int ct = 0; ct < 4; ct++)
                acc[rt][ct] = __builtin_amdgcn_mfma_f32_16x16x32_bf16(af[rt], bf[ct], acc[rt][ct], 0, 0, 0);
        __syncthreads();
    }

    // D layout: col=lane&15, row=(lane>>4)*4+r  [m89/m91 verified]
    #pragma unroll
    for (int rt = 0; rt < 4; rt++)
        #pragma unroll
        for (int ct = 0; ct < 4; ct++)
            #pragma unroll
            for (int r = 0; r < 4; r++) {
                int row = m0 + wm + rt * 16 + (lane >> 4) * 4 + r;
                int col = n0 + wn + ct * 16 + (lane & 15);
                Cp[(size_t)row * ldc + col] = acc[rt][ct][r];
            }
}

// ---------------------------------------------------------------------------
// Per-(b,t): gate + ve-add, RoPE + RMSNorm. qkv row = [q(1024)|k(512)|v(512)] f32.
// Writes Q (B,NH,T,HD), K/V (B,NKV,T,HD) in bf16.
// ---------------------------------------------------------------------------
__global__ __launch_bounds__(256) void qkv_post_kernel(
    const float* __restrict__ qkv, const float* __restrict__ x,
    const float* __restrict__ ve, const float* __restrict__ cosb,
    const float* __restrict__ sinb, const float* __restrict__ wgate,
    ushort* __restrict__ Qb, ushort* __restrict__ Kb, ushort* __restrict__ Vb)
{
    const int bt = blockIdx.x;
    const int b = bt >> 11, t = bt & 2047;
    const int tid = threadIdx.x;
    const int lane = tid & 63;
    const int w = tid >> 6;
    __shared__ float gateS[8];

    // gate[g] = 2*sigmoid(x[bt,:32] @ Wgate[:,g]); 32 threads per g
    {
        int g = tid >> 5, i = tid & 31;
        float p = x[(size_t)bt * CC + i] * wgate[i * 8 + g];
        #pragma unroll
        for (int off = 16; off; off >>= 1) p += __shfl_down(p, off, 32);
        if (i == 0) gateS[g] = 2.f / (1.f + __expf(-p));
    }
    __syncthreads();

    // RoPE + RMSNorm: heads 0..15 = q, 16..23 = k
    const float c = cosb[t * 32 + (lane & 31)];
    const float s = sinb[t * 32 + (lane & 31)];
    for (int hh = w; hh < 24; hh += 4) {
        const float* z = &qkv[(size_t)bt * 2048 + hh * 64];
        float v = z[lane];
        float other = __shfl_xor(v, 32);
        float x1 = (lane < 32) ? v : other;
        float x2 = (lane < 32) ? other : v;
        float val = (lane < 32) ? (x1 * c + x2 * s) : (-x1 * s + x2 * c);
        float ss = val * val;
        #pragma unroll
        for (int off = 32; off; off >>= 1) ss += __shfl_xor(ss, off);
        float scale = rsqrtf(ss * (1.f / 64.f) + 1.1920929e-07f);
        ushort ob = f2bf(val * scale);
        if (hh < 16) Qb[(((size_t)b * NH + hh) * TT + t) * HD + lane] = ob;
        else         Kb[(((size_t)b * NKV + (hh - 16)) * TT + t) * HD + lane] = ob;
    }

    // v = v + gate*ve
    for (int e = tid; e < NKV * HD; e += 256) {
        int kh = e >> 6, d = e & 63;
        float v = qkv[(size_t)bt * 2048 + 1536 + e] + gateS[kh] * ve[(size_t)bt * 512 + e];
        Vb[(((size_t)b * NKV + kh) * TT + t) * HD + d] = f2bf(v);
    }
}

// ---------------------------------------------------------------------------
// Flash attention: block = (qtile 64, head, batch); 4 waves x 16 q-rows.
// kv head = h/2; h>=8 -> windowed local mask.
// ---------------------------------------------------------------------------
__global__ __launch_bounds__(256) void attn_kernel(
    const ushort* __restrict__ Qb, const ushort* __restrict__ Kb,
    const ushort* __restrict__ Vb, ushort* __restrict__ Yb,
    const int* __restrict__ winp)
{
    const int qt = blockIdx.x, h = blockIdx.y, b = blockIdx.z;
    const int q0 = qt * 64;
    const int kv = h >> 1;
    const bool local = (h >= 8);
    int window = *winp;
    if (window < 0 || window > TT) window = TT;   // defensive; no-op when 512
    const int tid = threadIdx.x, lane = tid & 63, w = tid >> 6;

    __shared__ ushort Ks[64][72];      // [key][d]
    __shared__ ushort Vt[64][72];      // [d][key]
    __shared__ ushort Ps[4][16][72];   // per-wave P round-trip

    const ushort* qptr = &Qb[(((size_t)b * NH + h) * TT + q0 + w * 16 + (lane & 15)) * HD + (lane >> 4) * 8];
    short8 qf0 = *(const short8*)qptr;
    short8 qf1 = *(const short8*)(qptr + 32);

    float4v o[4] = {};
    float mrow[4], lrow[4];
    #pragma unroll
    for (int r = 0; r < 4; r++) { mrow[r] = -1e30f; lrow[r] = 0.f; }

    int jstart = 0;
    if (local) {
        int js = q0 - window; if (js < 0) js = 0;
        jstart = (js >> 6) << 6;
    }
    const ushort* Kbase = &Kb[((size_t)b * NKV + kv) * TT * HD];
    const ushort* Vbase = &Vb[((size_t)b * NKV + kv) * TT * HD];

    for (int j0 = jstart; j0 <= q0; j0 += 64) {
        #pragma unroll
        for (int i = 0; i < 2; i++) {
            int idx = tid + i * 256;
            int key = idx >> 3, part = (idx & 7) * 8;
            uint4 kvv = *(const uint4*)&Kbase[(size_t)(j0 + key) * HD + part];
            *(uint4*)&Ks[key][part] = kvv;
            ushort tmp[8];
            *(uint4*)tmp = *(const uint4*)&Vbase[(size_t)(j0 + key) * HD + part];
            #pragma unroll
            for (int jj = 0; jj < 8; jj++) Vt[part + jj][key] = tmp[jj];
        }
        __syncthreads();

        // S = Q @ K^T
        float4v sv[4];
        #pragma unroll
        for (int jt = 0; jt < 4; jt++) {
            short8 kf0 = *(const short8*)&Ks[jt * 16 + (lane & 15)][(lane >> 4) * 8];
            short8 kf1 = *(const short8*)&Ks[jt * 16 + (lane & 15)][32 + (lane >> 4) * 8];
            float4v z = {};
            z = __builtin_amdgcn_mfma_f32_16x16x32_bf16(qf0, kf0, z, 0, 0, 0);
            z = __builtin_amdgcn_mfma_f32_16x16x32_bf16(qf1, kf1, z, 0, 0, 0);
            sv[jt] = z;
        }

        // scale + mask (D layout: row=(lane>>4)*4+r, col=lane&15)
        const int rowb = q0 + w * 16 + (lane >> 4) * 4;
        #pragma unroll
        for (int jt = 0; jt < 4; jt++) {
            int col = j0 + jt * 16 + (lane & 15);
            #pragma unroll
            for (int r = 0; r < 4; r++) {
                int row = rowb + r;
                float v = sv[jt][r] * 0.125f;
                bool ok = (col <= row) && (!local || col >= row - window);
                sv[jt][r] = ok ? v : -1e30f;
            }
        }

        // online softmax (rows live in 16-lane groups)
        float pf[4][4];
        #pragma unroll
        for (int r = 0; r < 4; r++) {
            float mx = fmaxf(fmaxf(sv[0][r], sv[1][r]), fmaxf(sv[2][r], sv[3][r]));
            #pragma unroll
            for (int off = 1; off < 16; off <<= 1) mx = fmaxf(mx, __shfl_xor(mx, off));
            float mnew = fmaxf(mrow[r], mx);
            float alpha = __expf(fminf(mrow[r] - mnew, 0.f));
            mrow[r] = mnew;
            float ps = 0.f;
            #pragma unroll
            for (int jt = 0; jt < 4; jt++) {
                float sval = sv[jt][r];
                float p = (sval > -1e29f) ? __expf(fminf(sval - mnew, 0.f)) : 0.f;
                pf[jt][r] = p;
                ps += p;
            }
            #pragma unroll
            for (int off = 1; off < 16; off <<= 1) ps += __shfl_xor(ps, off);
            lrow[r] = lrow[r] * alpha + ps;
            #pragma unroll
            for (int ct = 0; ct < 4; ct++) o[ct][r] *= alpha;
        }

        // P: C-layout -> LDS -> A-layout
        #pragma unroll
        for (int jt = 0; jt < 4; jt++)
            #pragma unroll
            for (int r = 0; r < 4; r++)
                Ps[w][(lane >> 4) * 4 + r][jt * 16 + (lane & 15)] = f2bf(pf[jt][r]);
        __syncthreads();

        short8 pf0 = *(const short8*)&Ps[w][lane & 15][(lane >> 4) * 8];
        short8 pf1 = *(const short8*)&Ps[w][lane & 15][32 + (lane >> 4) * 8];
        #pragma unroll
        for (int ct = 0; ct < 4; ct++) {
            short8 vf0 = *(const short8*)&Vt[ct * 16 + (lane & 15)][(lane >> 4) * 8];
            short8 vf1 = *(const short8*)&Vt[ct * 16 + (lane & 15)][32 + (lane >> 4) * 8];
            o[ct] = __builtin_amdgcn_mfma_f32_16x16x32_bf16(pf0, vf0, o[ct], 0, 0, 0);
            o[ct] = __builtin_amdgcn_mfma_f32_16x16x32_bf16(pf1, vf1, o[ct], 0, 0, 0);
        }
        __syncthreads();
    }

    // normalize + write y (B,T,NH*HD) bf16
    #pragma unroll
    for (int ct = 0; ct < 4; ct++)
        #pragma unroll
        for (int r = 0; r < 4; r++) {
            int trow = q0 + w * 16 + (lane >> 4) * 4 + r;
            int col = h * HD + ct * 16 + (lane & 15);
            float denom = fmaxf(lrow[r], 1e-20f);
            Yb[((size_t)b * TT + trow) * CC + col] = f2bf(o[ct][r] / denom);
        }
}

// ---------------------------------------------------------------------------
extern "C" void kernel_launch(void* const* d_in, const int* in_sizes, int n_in,
                              void* d_out, int out_size, void* d_ws, size_t ws_size,
                              hipStream_t stream) {
    (void)in_sizes; (void)n_in; (void)out_size; (void)ws_size;
    const float* x     = (const float*)d_in[0];
    const float* ve    = (const float*)d_in[1];
    const float* cosb  = (const float*)d_in[2];
    const float* sinb  = (const float*)d_in[3];
    const float* Wq    = (const float*)d_in[4];
    const float* Wk    = (const float*)d_in[5];
    const float* Wv    = (const float*)d_in[6];
    const float* Wproj = (const float*)d_in[7];
    const float* Wgate = (const float*)d_in[8];
    const int*   winp  = (const int*)d_in[9];
    float* out = (float*)d_out;

    char* ws = (char*)d_ws;
    float*  qkv  = (float*)ws;                      // 32 MiB (dead after qkv_post)
    ushort* Yb   = (ushort*)ws;                     // 8 MiB, overlays qkv
    ushort* xb   = (ushort*)(ws + 33554432);        // 8 MiB
    ushort* Wqkvb= (ushort*)(ws + 41943040);        // 4 MiB
    ushort* Wpb  = (ushort*)(ws + 46137344);        // 2 MiB
    ushort* Qb   = (ushort*)(ws + 48234496);        // 8 MiB
    ushort* Kb   = (ushort*)(ws + 56623104);        // 4 MiB
    ushort* Vb   = (ushort*)(ws + 60817408);        // 4 MiB  (total 62 MiB)

    dim3 blk(256);
    // one-shot conversions
    conv_kernel<<<dim3(4096), blk, 0, stream>>>(x, xb, BB * TT * CC);
    pack_qkv_w_kernel<<<dim3(8192), blk, 0, stream>>>(Wq, Wk, Wv, Wqkvb);
    conv_kernel<<<dim3(1024), blk, 0, stream>>>(Wproj, Wpb, CC * CC);
    // fused QKV projection (f32 out, row = [q|k|v])
    gemm_kernel<<<dim3(32, 16), blk, 0, stream>>>(xb, Wqkvb, qkv, 4096, 2048, 1024, 2048);
    // gate/ve/rope/rmsnorm
    qkv_post_kernel<<<dim3(BB * TT), blk, 0, stream>>>(qkv, x, ve, cosb, sinb, Wgate, Qb, Kb, Vb);
    // attention
    attn_kernel<<<dim3(TT / 64, NH, BB), blk, 0, stream>>>(Qb, Kb, Vb, Yb, winp);
    // output projection -> f32 d_out
    gemm_kernel<<<dim3(32, 8), blk, 0, stream>>>(Yb, Wpb, out, 4096, 1024, 1024, 1024);
}